// Round 7
// baseline (306.420 us; speedup 1.0000x reference)
//
#include <hip/hip_runtime.h>

#define BATCH  4096
#define SEQT   2048
#define HID    10
#define NSEG   16
#define SEGLEN (SEQT / NSEG)     // 128
#define WARM   64

#define LOG2E 1.44269504088896340736f

typedef _Float16 h2 __attribute__((ext_vector_type(2)));

__device__ __forceinline__ float rcp_f(float v) { return __builtin_amdgcn_rcpf(v); }
__device__ __forceinline__ float exp2_f(float v) {
#if __has_builtin(__builtin_amdgcn_exp2f)
    return __builtin_amdgcn_exp2f(v);
#else
    return __expf(v * 0.6931471805599453f);
#endif
}

#if __has_builtin(__builtin_amdgcn_fdot2)
__device__ __forceinline__ float fdot2(h2 a, h2 b, float c) {
    return __builtin_amdgcn_fdot2(a, b, c, false);
}
#else
__device__ __forceinline__ float fdot2(h2 a, h2 b, float c) {
    return fmaf((float)a.x, (float)b.x, fmaf((float)a.y, (float)b.y, c));
}
#endif

template <int CTRL>
__device__ __forceinline__ int dppi(int v) {
    return __builtin_amdgcn_mov_dpp(v, CTRL, 0xf, 0xf, true);
}
// swap within lane pairs: quad_perm [1,0,3,2]
__device__ __forceinline__ int   pswapi(int v)  { return dppi<0xB1>(v); }
__device__ __forceinline__ float pswapf(float v) {
    return __builtin_bit_cast(float, pswapi(__builtin_bit_cast(int, v)));
}

// One step, S = literal 0..15.
// K-vector (12 elems, both lanes, own-slots-first order per parity):
//   lane0: (h0,h1)(h2,h3)(h4,x) | (h5,h6)(h7,h8)(h9,·)
//   lane1: (h5,h6)(h7,h8)(h9,·) | (h0,h1)(h2,h3)(h4,x)
// '·' slots carry weight 0. Bias (pre-scaled) is the fdot2 chain init.
// Weights pre-scaled (-log2e sigmoid rows, -2log2e tanh row) so
// i=1/(1+Ei), f=1/(1+Ef), g=(1-Eg)/(1+Eg), o=1/(1+Eo);
// c' = (c*Pi*Pg + Mg*Pf)/(Pf*Pi*Pg);  h = (1-Ec)/(Po*(1+Ec)).
#define STEP(S, STORE_OK)                                                      \
  {                                                                            \
    /* x[tc+S] lives in lane (S>>3), comp S&7; garbage in other lane is */     \
    /* harmless (zero-weighted slot). */                                       \
    const float xt = ((S) < 8) ? xq[(S) & 7] : pswapf(xq[(S) & 7]);            \
    const int o0 = __builtin_bit_cast(int,                                     \
        __builtin_amdgcn_cvt_pkrtz(ho[0], ho[1]));                             \
    const int o1 = __builtin_bit_cast(int,                                     \
        __builtin_amdgcn_cvt_pkrtz(ho[2], ho[3]));                             \
    const int o2 = __builtin_bit_cast(int,                                     \
        __builtin_amdgcn_cvt_pkrtz(ho[4], xt));                                \
    const h2 hx0 = __builtin_bit_cast(h2, o0);                                 \
    const h2 hx1 = __builtin_bit_cast(h2, o1);                                 \
    const h2 hx2 = __builtin_bit_cast(h2, o2);                                 \
    const h2 hx3 = __builtin_bit_cast(h2, pswapi(o0));                         \
    const h2 hx4 = __builtin_bit_cast(h2, pswapi(o1));                         \
    const h2 hx5 = __builtin_bit_cast(h2, pswapi(o2));                         \
    {   /* out[t-1]: own 5-dot (f32) + one pair-swap add */                    \
      float rp = fmaf(ho[4], wo[4], fmaf(ho[3], wo[3],                         \
                 fmaf(ho[2], wo[2], fmaf(ho[1], wo[1], ho[0] * wo[0]))));      \
      rp += pswapf(rp);                                                        \
      const float r = rp + bout;                                               \
      constexpr int PP = ((S) + 15) & 15;                                      \
      if (kl[PP >> 3]) keep[PP & 7] = r;                                       \
    }                                                                          \
    if ((S) == 0 && (STORE_OK)) {                                              \
      *(float4*)(optr + tc - 16) = make_float4(keep[0], keep[1],               \
                                               keep[2], keep[3]);              \
      *(float4*)(optr + tc - 12) = make_float4(keep[4], keep[5],               \
                                               keep[6], keep[7]);              \
    }                                                                          \
    _Pragma("unroll")                                                          \
    for (int k = 0; k < 5; ++k) {                                              \
      const float pi = fdot2(hx5, w16[k][0][5], fdot2(hx4, w16[k][0][4],       \
          fdot2(hx3, w16[k][0][3], fdot2(hx2, w16[k][0][2],                    \
          fdot2(hx1, w16[k][0][1], fdot2(hx0, w16[k][0][0], wb[k][0]))))));    \
      const float pf = fdot2(hx5, w16[k][1][5], fdot2(hx4, w16[k][1][4],       \
          fdot2(hx3, w16[k][1][3], fdot2(hx2, w16[k][1][2],                    \
          fdot2(hx1, w16[k][1][1], fdot2(hx0, w16[k][1][0], wb[k][1]))))));    \
      const float pg = fdot2(hx5, w16[k][2][5], fdot2(hx4, w16[k][2][4],       \
          fdot2(hx3, w16[k][2][3], fdot2(hx2, w16[k][2][2],                    \
          fdot2(hx1, w16[k][2][1], fdot2(hx0, w16[k][2][0], wb[k][2]))))));    \
      const float po = fdot2(hx5, w16[k][3][5], fdot2(hx4, w16[k][3][4],       \
          fdot2(hx3, w16[k][3][3], fdot2(hx2, w16[k][3][2],                    \
          fdot2(hx1, w16[k][3][1], fdot2(hx0, w16[k][3][0], wb[k][3]))))));    \
      const float Ei = exp2_f(pi), Ef = exp2_f(pf);                            \
      const float Eg = exp2_f(pg), Eo = exp2_f(po);                            \
      const float Pi = 1.0f + Ei, Pf = 1.0f + Ef;                              \
      const float Pg = 1.0f + Eg, Po = 1.0f + Eo;                              \
      const float Mg = 1.0f - Eg;                                              \
      const float A   = Pi * Pg;                                               \
      const float den = Pf * A;                                                \
      const float num = fmaf(cc[k], A, Mg * Pf);                               \
      const float cn  = num * rcp_f(den);                                      \
      cc[k] = cn;                                                              \
      const float Ec   = exp2_f(cn * (-2.0f * LOG2E));                         \
      const float den2 = Po * (1.0f + Ec);                                     \
      ho[k] = (1.0f - Ec) * rcp_f(den2);                                       \
    }                                                                          \
  }

// 2 lanes/chain (lane parity l owns units 5l..5l+4 — no padding), 32
// chains/wave. 16-way sequence split w/ 64-step warm-up -> 65536 vchains ->
// 2048 waves = 2/SIMD. No LDS; all cross-lane via pair-swap DPP.
__global__ __launch_bounds__(256, 2) void lstm_fused(
    const float* __restrict__ x,      // [B, T, 1]
    const float* __restrict__ W_ih,   // [4H, 1]
    const float* __restrict__ W_hh,   // [4H, H]
    const float* __restrict__ b_ih,   // [4H]
    const float* __restrict__ b_hh,   // [4H]
    const float* __restrict__ W_out,  // [1, H]
    const float* __restrict__ b_out,  // [1]
    float* __restrict__ out)          // [B, T, 1]
{
    const int tid = threadIdx.x;
    const int l   = tid & 1;                        // parity within pair
    const int vc  = blockIdx.x * 128 + (tid >> 1);  // virtual chain 0..65535
    const int seg = vc >> 12;                       // block-uniform (32 blk/seg)
    const int b   = vc & (BATCH - 1);

    const int t_main = seg * SEGLEN;
    const int t0     = seg ? (t_main - WARM) : 0;
    const int tend   = t_main + SEGLEN;

    // w16[unit][gate][slot]: f16 pairs in own-slots-first order (see STEP).
    h2    w16[5][4][6];
    float wb[5][4];
    #pragma unroll
    for (int k = 0; k < 5; ++k) {
        const int u = 5 * l + k;
        #pragma unroll
        for (int g = 0; g < 4; ++g) {
            const int   r  = g * HID + u;           // PyTorch gate order i,f,g,o
            const float sc = (g == 2) ? (-2.0f * LOG2E) : (-LOG2E);
            wb[k][g] = (b_ih[r] + b_hh[r]) * sc;
            #pragma unroll
            for (int slot = 0; slot < 6; ++slot) {
                const int p = (slot < 3) ? l : (1 - l);  // pair's owner parity
                const int w = slot % 3;
                float xw, yw;
                if (w < 2) {
                    xw = W_hh[r * HID + 5 * p + 2 * w]     * sc;
                    yw = W_hh[r * HID + 5 * p + 2 * w + 1] * sc;
                } else {
                    xw = W_hh[r * HID + 5 * p + 4] * sc;
                    yw = (p == 0) ? W_ih[r] * sc : 0.0f;   // x slot / dead slot
                }
                w16[k][g][slot] = h2{(_Float16)xw, (_Float16)yw};
            }
        }
    }
    float wo[5];
    #pragma unroll
    for (int k = 0; k < 5; ++k) wo[k] = W_out[5 * l + k];
    const float bout = b_out[0];

    const bool kl[2] = {l == 0, l == 1};

    const float* xptr = x   + (size_t)b * SEQT + 8 * l;
    float*       optr = out + (size_t)b * SEQT + 8 * l;

    float ho[5] = {0.f, 0.f, 0.f, 0.f, 0.f};
    float cc[5] = {0.f, 0.f, 0.f, 0.f, 0.f};
    float keep[8] = {0.f, 0.f, 0.f, 0.f, 0.f, 0.f, 0.f, 0.f};
    float xq[8], xqn[8];

    {   // first chunk's x: lane l holds x[t0+8l .. t0+8l+8)
        const float4 a = *(const float4*)(xptr + t0);
        const float4 c = *(const float4*)(xptr + t0 + 4);
        xq[0] = a.x; xq[1] = a.y; xq[2] = a.z; xq[3] = a.w;
        xq[4] = c.x; xq[5] = c.y; xq[6] = c.z; xq[7] = c.w;
    }

    for (int tc = t0; tc < tend; tc += 16) {
        if (tc + 16 < tend) {
            const float4 a = *(const float4*)(xptr + tc + 16);
            const float4 c = *(const float4*)(xptr + tc + 20);
            xqn[0] = a.x; xqn[1] = a.y; xqn[2] = a.z; xqn[3] = a.w;
            xqn[4] = c.x; xqn[5] = c.y; xqn[6] = c.z; xqn[7] = c.w;
        }
        const bool store_ok = (tc > t_main);
        STEP(0, store_ok)
        STEP(1, false) STEP(2, false) STEP(3, false) STEP(4, false)
        STEP(5, false) STEP(6, false) STEP(7, false) STEP(8, false)
        STEP(9, false) STEP(10, false) STEP(11, false) STEP(12, false)
        STEP(13, false) STEP(14, false) STEP(15, false)
        #pragma unroll
        for (int i = 0; i < 8; ++i) xq[i] = xqn[i];
    }

    // epilogue: out[tend-1] from final h, store last chunk
    {
        float rp = fmaf(ho[4], wo[4], fmaf(ho[3], wo[3],
                   fmaf(ho[2], wo[2], fmaf(ho[1], wo[1], ho[0] * wo[0]))));
        rp += pswapf(rp);
        const float r = rp + bout;
        if (kl[1]) keep[7] = r;                      // position 15
        *(float4*)(optr + tend - 16) = make_float4(keep[0], keep[1],
                                                   keep[2], keep[3]);
        *(float4*)(optr + tend - 12) = make_float4(keep[4], keep[5],
                                                   keep[6], keep[7]);
    }
}

extern "C" void kernel_launch(void* const* d_in, const int* in_sizes, int n_in,
                              void* d_out, int out_size, void* d_ws, size_t ws_size,
                              hipStream_t stream) {
    const float* x     = (const float*)d_in[0];
    const float* W_ih  = (const float*)d_in[1];
    const float* W_hh  = (const float*)d_in[2];
    const float* b_ih  = (const float*)d_in[3];
    const float* b_hh  = (const float*)d_in[4];
    const float* W_out = (const float*)d_in[5];
    const float* b_out = (const float*)d_in[6];
    float* out = (float*)d_out;

    dim3 grid(NSEG * BATCH / 128);   // 512 blocks x 128 vchains -> 2048 waves
    dim3 block(256);
    lstm_fused<<<grid, block, 0, stream>>>(x, W_ih, W_hh, b_ih, b_hh,
                                           W_out, b_out, out);
}

// Round 8
// 304.798 us; speedup vs baseline: 1.0053x; 1.0053x over previous
//
#include <hip/hip_runtime.h>

#define BATCH  4096
#define SEQT   2048
#define HID    10
#define NSEG   16
#define SEGLEN (SEQT / NSEG)     // 128
#define WARM   64

#define LOG2E 1.44269504088896340736f

typedef _Float16 h2 __attribute__((ext_vector_type(2)));

__device__ __forceinline__ float rcp_f(float v) { return __builtin_amdgcn_rcpf(v); }
__device__ __forceinline__ float exp2_f(float v) {
#if __has_builtin(__builtin_amdgcn_exp2f)
    return __builtin_amdgcn_exp2f(v);
#else
    return __expf(v * 0.6931471805599453f);
#endif
}

#if __has_builtin(__builtin_amdgcn_fdot2)
__device__ __forceinline__ float fdot2(h2 a, h2 b, float c) {
    return __builtin_amdgcn_fdot2(a, b, c, false);
}
#else
__device__ __forceinline__ float fdot2(h2 a, h2 b, float c) {
    return fmaf((float)a.x, (float)b.x, fmaf((float)a.y, (float)b.y, c));
}
#endif

template <int CTRL>
__device__ __forceinline__ int dppi(int v) {
    return __builtin_amdgcn_mov_dpp(v, CTRL, 0xf, 0xf, true);
}
// swap within lane pairs: quad_perm [1,0,3,2]
__device__ __forceinline__ int   pswapi(int v)  { return dppi<0xB1>(v); }
__device__ __forceinline__ float pswapf(float v) {
    return __builtin_bit_cast(float, pswapi(__builtin_bit_cast(int, v)));
}

// One step, S = literal 0..15.
// K-vector (12 elems, both lanes, own-slots-first order per parity):
//   lane0: (h0,h1)(h2,h3)(h4,x) | (h5,h6)(h7,h8)(h9,·)
//   lane1: (h5,h6)(h7,h8)(h9,·) | (h0,h1)(h2,h3)(h4,x)
// '·' slots carry weight 0. Bias (pre-scaled) is the fdot2 chain init.
// Weights pre-scaled (-log2e sigmoid rows, -2log2e tanh row) so
// i=1/(1+Ei), f=1/(1+Ef), g=(1-Eg)/(1+Eg), o=1/(1+Eo);
// c' = (c*Pi*Pg + Mg*Pf)/(Pf*Pi*Pg);  h = (1-Ec)/(Po*(1+Ec)).
#define STEP(S, STORE_OK)                                                      \
  {                                                                            \
    /* x[tc+S]: owner lane (S>>3) passes it through the swapped x-slot; the */ \
    /* non-owner's own x-slot weight is 0, so its garbage is harmless. */      \
    const float xt = ((S) < 8) ? xq[(S) & 7] : pswapf(xq[(S) & 7]);            \
    const int o0 = __builtin_bit_cast(int,                                     \
        __builtin_amdgcn_cvt_pkrtz(ho[0], ho[1]));                             \
    const int o1 = __builtin_bit_cast(int,                                     \
        __builtin_amdgcn_cvt_pkrtz(ho[2], ho[3]));                             \
    const int o2 = __builtin_bit_cast(int,                                     \
        __builtin_amdgcn_cvt_pkrtz(ho[4], xt));                                \
    const h2 hx0 = __builtin_bit_cast(h2, o0);                                 \
    const h2 hx1 = __builtin_bit_cast(h2, o1);                                 \
    const h2 hx2 = __builtin_bit_cast(h2, o2);                                 \
    const h2 hx3 = __builtin_bit_cast(h2, pswapi(o0));                         \
    const h2 hx4 = __builtin_bit_cast(h2, pswapi(o1));                         \
    const h2 hx5 = __builtin_bit_cast(h2, pswapi(o2));                         \
    {   /* out[t-1]: own 5-dot (f32) + one pair-swap add */                    \
      float rp = fmaf(ho[4], wo[4], fmaf(ho[3], wo[3],                         \
                 fmaf(ho[2], wo[2], fmaf(ho[1], wo[1], ho[0] * wo[0]))));      \
      rp += pswapf(rp);                                                        \
      const float r = rp + bout;                                               \
      constexpr int PP = ((S) + 15) & 15;                                      \
      if (kl[PP >> 3]) keep[PP & 7] = r;                                       \
    }                                                                          \
    if ((S) == 0 && (STORE_OK)) {                                              \
      *(float4*)(optr + tc - 16) = make_float4(keep[0], keep[1],               \
                                               keep[2], keep[3]);              \
      *(float4*)(optr + tc - 12) = make_float4(keep[4], keep[5],               \
                                               keep[6], keep[7]);              \
    }                                                                          \
    _Pragma("unroll")                                                          \
    for (int k = 0; k < 5; ++k) {                                              \
      const float pi = fdot2(hx5, w16[k][0][5], fdot2(hx4, w16[k][0][4],       \
          fdot2(hx3, w16[k][0][3], fdot2(hx2, w16[k][0][2],                    \
          fdot2(hx1, w16[k][0][1], fdot2(hx0, w16[k][0][0], wb[k][0]))))));    \
      const float pf = fdot2(hx5, w16[k][1][5], fdot2(hx4, w16[k][1][4],       \
          fdot2(hx3, w16[k][1][3], fdot2(hx2, w16[k][1][2],                    \
          fdot2(hx1, w16[k][1][1], fdot2(hx0, w16[k][1][0], wb[k][1]))))));    \
      const float pg = fdot2(hx5, w16[k][2][5], fdot2(hx4, w16[k][2][4],       \
          fdot2(hx3, w16[k][2][3], fdot2(hx2, w16[k][2][2],                    \
          fdot2(hx1, w16[k][2][1], fdot2(hx0, w16[k][2][0], wb[k][2]))))));    \
      const float po = fdot2(hx5, w16[k][3][5], fdot2(hx4, w16[k][3][4],       \
          fdot2(hx3, w16[k][3][3], fdot2(hx2, w16[k][3][2],                    \
          fdot2(hx1, w16[k][3][1], fdot2(hx0, w16[k][3][0], wb[k][3]))))));    \
      const float Ei = exp2_f(pi), Ef = exp2_f(pf);                            \
      const float Eg = exp2_f(pg), Eo = exp2_f(po);                            \
      const float Pi = 1.0f + Ei, Pf = 1.0f + Ef;                              \
      const float Pg = 1.0f + Eg, Po = 1.0f + Eo;                              \
      const float Mg = 1.0f - Eg;                                              \
      const float A   = Pi * Pg;                                               \
      const float den = Pf * A;                                                \
      const float num = fmaf(cc[k], A, Mg * Pf);                               \
      const float cn  = num * rcp_f(den);                                      \
      cc[k] = cn;                                                              \
      const float Ec   = exp2_f(cn * (-2.0f * LOG2E));                         \
      const float den2 = Po * (1.0f + Ec);                                     \
      ho[k] = (1.0f - Ec) * rcp_f(den2);                                       \
    }                                                                          \
  }

// 2 lanes/chain (lane parity l owns units 5l..5l+4 — no padding), 32
// chains/wave. 16-way sequence split w/ 64-step warm-up -> 65536 vchains ->
// 2048 waves = 2/SIMD. No LDS; all cross-lane via pair-swap DPP.
// waves_per_eu(2,2): pin allocator at 2 waves/EU -> 256-VGPR budget, no
// spill (R7: launch_bounds(256,2) let RA target 4 waves/EU -> 128 VGPR +
// ~34MB scratch writes).
__global__
__attribute__((amdgpu_flat_work_group_size(256, 256), amdgpu_waves_per_eu(2, 2)))
void lstm_fused(
    const float* __restrict__ x,      // [B, T, 1]
    const float* __restrict__ W_ih,   // [4H, 1]
    const float* __restrict__ W_hh,   // [4H, H]
    const float* __restrict__ b_ih,   // [4H]
    const float* __restrict__ b_hh,   // [4H]
    const float* __restrict__ W_out,  // [1, H]
    const float* __restrict__ b_out,  // [1]
    float* __restrict__ out)          // [B, T, 1]
{
    const int tid = threadIdx.x;
    const int l   = tid & 1;                        // parity within pair
    const int vc  = blockIdx.x * 128 + (tid >> 1);  // virtual chain 0..65535
    const int seg = vc >> 12;                       // block-uniform (32 blk/seg)
    const int b   = vc & (BATCH - 1);

    const int t_main = seg * SEGLEN;
    const int t0     = seg ? (t_main - WARM) : 0;
    const int tend   = t_main + SEGLEN;

    // w16[unit][gate][slot]: f16 pairs in own-slots-first order (see STEP).
    h2    w16[5][4][6];
    float wb[5][4];
    #pragma unroll
    for (int k = 0; k < 5; ++k) {
        const int u = 5 * l + k;
        #pragma unroll
        for (int g = 0; g < 4; ++g) {
            const int   r  = g * HID + u;           // PyTorch gate order i,f,g,o
            const float sc = (g == 2) ? (-2.0f * LOG2E) : (-LOG2E);
            wb[k][g] = (b_ih[r] + b_hh[r]) * sc;
            #pragma unroll
            for (int slot = 0; slot < 6; ++slot) {
                const int p = (slot < 3) ? l : (1 - l);  // pair's owner parity
                const int w = slot % 3;
                float xw, yw;
                if (w < 2) {
                    xw = W_hh[r * HID + 5 * p + 2 * w]     * sc;
                    yw = W_hh[r * HID + 5 * p + 2 * w + 1] * sc;
                } else {
                    xw = W_hh[r * HID + 5 * p + 4] * sc;
                    yw = (p == 0) ? W_ih[r] * sc : 0.0f;   // x slot / dead slot
                }
                w16[k][g][slot] = h2{(_Float16)xw, (_Float16)yw};
            }
        }
    }
    float wo[5];
    #pragma unroll
    for (int k = 0; k < 5; ++k) wo[k] = W_out[5 * l + k];
    const float bout = b_out[0];

    const bool kl[2] = {l == 0, l == 1};

    const float* xptr = x   + (size_t)b * SEQT + 8 * l;
    float*       optr = out + (size_t)b * SEQT + 8 * l;

    float ho[5] = {0.f, 0.f, 0.f, 0.f, 0.f};
    float cc[5] = {0.f, 0.f, 0.f, 0.f, 0.f};
    float keep[8] = {0.f, 0.f, 0.f, 0.f, 0.f, 0.f, 0.f, 0.f};
    float xq[8], xqn[8];

    {   // first chunk's x: lane l holds x[t0+8l .. t0+8l+8)
        const float4 a = *(const float4*)(xptr + t0);
        const float4 c = *(const float4*)(xptr + t0 + 4);
        xq[0] = a.x; xq[1] = a.y; xq[2] = a.z; xq[3] = a.w;
        xq[4] = c.x; xq[5] = c.y; xq[6] = c.z; xq[7] = c.w;
    }

    for (int tc = t0; tc < tend; tc += 16) {
        if (tc + 16 < tend) {
            const float4 a = *(const float4*)(xptr + tc + 16);
            const float4 c = *(const float4*)(xptr + tc + 20);
            xqn[0] = a.x; xqn[1] = a.y; xqn[2] = a.z; xqn[3] = a.w;
            xqn[4] = c.x; xqn[5] = c.y; xqn[6] = c.z; xqn[7] = c.w;
        }
        const bool store_ok = (tc > t_main);
        STEP(0, store_ok)
        STEP(1, false) STEP(2, false) STEP(3, false) STEP(4, false)
        STEP(5, false) STEP(6, false) STEP(7, false) STEP(8, false)
        STEP(9, false) STEP(10, false) STEP(11, false) STEP(12, false)
        STEP(13, false) STEP(14, false) STEP(15, false)
        #pragma unroll
        for (int i = 0; i < 8; ++i) xq[i] = xqn[i];
    }

    // epilogue: out[tend-1] from final h, store last chunk
    {
        float rp = fmaf(ho[4], wo[4], fmaf(ho[3], wo[3],
                   fmaf(ho[2], wo[2], fmaf(ho[1], wo[1], ho[0] * wo[0]))));
        rp += pswapf(rp);
        const float r = rp + bout;
        if (kl[1]) keep[7] = r;                      // position 15
        *(float4*)(optr + tend - 16) = make_float4(keep[0], keep[1],
                                                   keep[2], keep[3]);
        *(float4*)(optr + tend - 12) = make_float4(keep[4], keep[5],
                                                   keep[6], keep[7]);
    }
}

extern "C" void kernel_launch(void* const* d_in, const int* in_sizes, int n_in,
                              void* d_out, int out_size, void* d_ws, size_t ws_size,
                              hipStream_t stream) {
    const float* x     = (const float*)d_in[0];
    const float* W_ih  = (const float*)d_in[1];
    const float* W_hh  = (const float*)d_in[2];
    const float* b_ih  = (const float*)d_in[3];
    const float* b_hh  = (const float*)d_in[4];
    const float* W_out = (const float*)d_in[5];
    const float* b_out = (const float*)d_in[6];
    float* out = (float*)d_out;

    dim3 grid(NSEG * BATCH / 128);   // 512 blocks x 128 vchains -> 2048 waves
    dim3 block(256);
    lstm_fused<<<grid, block, 0, stream>>>(x, W_ih, W_hh, b_ih, b_hh,
                                           W_out, b_out, out);
}

// Round 9
// 286.135 us; speedup vs baseline: 1.0709x; 1.0652x over previous
//
#include <hip/hip_runtime.h>

#define BATCH  4096
#define SEQT   2048
#define HID    10
#define NSEG   16
#define SEGLEN (SEQT / NSEG)     // 128
#define WARM   64

#define LOG2E 1.44269504088896340736f

typedef _Float16 h2 __attribute__((ext_vector_type(2)));

__device__ __forceinline__ float rcp_f(float v) { return __builtin_amdgcn_rcpf(v); }
__device__ __forceinline__ float exp2_f(float v) {
#if __has_builtin(__builtin_amdgcn_exp2f)
    return __builtin_amdgcn_exp2f(v);
#else
    return __expf(v * 0.6931471805599453f);
#endif
}

#if __has_builtin(__builtin_amdgcn_fdot2)
__device__ __forceinline__ float fdot2(h2 a, h2 b, float c) {
    return __builtin_amdgcn_fdot2(a, b, c, false);
}
#else
__device__ __forceinline__ float fdot2(h2 a, h2 b, float c) {
    return fmaf((float)a.x, (float)b.x, fmaf((float)a.y, (float)b.y, c));
}
#endif

template <int CTRL>
__device__ __forceinline__ int dppi(int v) {
    return __builtin_amdgcn_mov_dpp(v, CTRL, 0xf, 0xf, true);
}
__device__ __forceinline__ int   pswapi(int v)  { return dppi<0xB1>(v); }  // [1,0,3,2]
__device__ __forceinline__ float pswapf(float v) {
    return __builtin_bit_cast(float, pswapi(__builtin_bit_cast(int, v)));
}
__device__ __forceinline__ int pk16(float a, float b) {
    return __builtin_bit_cast(int, __builtin_amdgcn_cvt_pkrtz(a, b));
}

// One step, S = literal 0..7.
// K-vector (12 elems exactly — h0..h9, x, 1):
//   lane l packs o0=(h_{5l},h_{5l+1}) o1=(h_{5l+2},h_{5l+3}) o2=(h_{5l+4}, t)
//   with t = x[tc+S] on lane0, 1.0 on lane1. hx0..2 = own packs,
//   hx3..5 = pair-swapped. Weight slot2 of parity-p group = (whh4p, p==0?wih:bias)
//   so x·wih and 1·bias ride the f16 dot — no separate f32 bias regs.
// Weights pre-scaled (-log2e sigmoid rows, -2log2e tanh row):
//   i=1/(1+Ei), f=1/(1+Ef), g=(1-Eg)/(1+Eg), o=1/(1+Eo);
//   c' = (c*Pi*Pg + Mg*Pf)/(Pf*Pi*Pg);  h = (1-Ec)/(Po*(1+Ec)).
// sched_barrier(0) per step: steps are serially dependent (h,c) — blocking
// cross-step hoisting caps register-pressure spikes (R7/R8 spilled).
#define STEP(S, STORE_OK)                                                      \
  {                                                                            \
    const float xs  = ((S) < 4) ? xq[(S) & 3] : pswapf(xq[(S) & 3]);           \
    const float tpk = (l == 0) ? xs : 1.0f;                                    \
    const int o0 = pk16(ho[0], ho[1]);                                         \
    const int o1 = pk16(ho[2], ho[3]);                                         \
    const int o2 = pk16(ho[4], tpk);                                           \
    const h2 hx0 = __builtin_bit_cast(h2, o0);                                 \
    const h2 hx1 = __builtin_bit_cast(h2, o1);                                 \
    const h2 hx2 = __builtin_bit_cast(h2, o2);                                 \
    const h2 hx3 = __builtin_bit_cast(h2, pswapi(o0));                         \
    const h2 hx4 = __builtin_bit_cast(h2, pswapi(o1));                         \
    const h2 hx5 = __builtin_bit_cast(h2, pswapi(o2));                         \
    {   /* out[t-1]: 3 fdot2 on own packs (wo2.y=0 kills the t slot) */        \
      float rp = fdot2(hx2, wo2, fdot2(hx1, wo1, fdot2(hx0, wo0, 0.0f)));      \
      rp += pswapf(rp);                                                        \
      const float r = rp + bout;                                               \
      constexpr int PP = ((S) + 7) & 7;                                        \
      if (l == (PP >> 2)) keep[PP & 3] = r;                                    \
    }                                                                          \
    if ((S) == 0 && (STORE_OK))                                                \
      *(float4*)(optr + tc - 8) = make_float4(keep[0], keep[1],                \
                                              keep[2], keep[3]);               \
    _Pragma("unroll")                                                          \
    for (int k = 0; k < 5; ++k) {                                              \
      const float pi = fdot2(hx5, w16[k][0][5], fdot2(hx4, w16[k][0][4],       \
          fdot2(hx3, w16[k][0][3], fdot2(hx2, w16[k][0][2],                    \
          fdot2(hx1, w16[k][0][1], fdot2(hx0, w16[k][0][0], 0.0f))))));        \
      const float pf = fdot2(hx5, w16[k][1][5], fdot2(hx4, w16[k][1][4],       \
          fdot2(hx3, w16[k][1][3], fdot2(hx2, w16[k][1][2],                    \
          fdot2(hx1, w16[k][1][1], fdot2(hx0, w16[k][1][0], 0.0f))))));        \
      const float pg = fdot2(hx5, w16[k][2][5], fdot2(hx4, w16[k][2][4],       \
          fdot2(hx3, w16[k][2][3], fdot2(hx2, w16[k][2][2],                    \
          fdot2(hx1, w16[k][2][1], fdot2(hx0, w16[k][2][0], 0.0f))))));        \
      const float po = fdot2(hx5, w16[k][3][5], fdot2(hx4, w16[k][3][4],       \
          fdot2(hx3, w16[k][3][3], fdot2(hx2, w16[k][3][2],                    \
          fdot2(hx1, w16[k][3][1], fdot2(hx0, w16[k][3][0], 0.0f))))));        \
      const float Ei = exp2_f(pi), Ef = exp2_f(pf);                            \
      const float Eg = exp2_f(pg), Eo = exp2_f(po);                            \
      const float Pi = 1.0f + Ei, Pf = 1.0f + Ef;                              \
      const float Pg = 1.0f + Eg, Po = 1.0f + Eo;                              \
      const float Mg = 1.0f - Eg;                                              \
      const float A   = Pi * Pg;                                               \
      const float den = Pf * A;                                                \
      const float num = fmaf(cc[k], A, Mg * Pf);                               \
      const float cn  = num * rcp_f(den);                                      \
      cc[k] = cn;                                                              \
      const float Ec   = exp2_f(cn * (-2.0f * LOG2E));                         \
      const float den2 = Po * (1.0f + Ec);                                     \
      ho[k] = (1.0f - Ec) * rcp_f(den2);                                       \
    }                                                                          \
    __builtin_amdgcn_sched_barrier(0);                                         \
  }

// 2 lanes/chain (lane parity l owns units 5l..5l+4 — zero padding), 32
// chains/wave. 16-way sequence split w/ 64-step warm-up -> 65536 vchains ->
// 2048 waves = 2/SIMD. No LDS; all cross-lane via pair-swap DPP.
__global__
__attribute__((amdgpu_flat_work_group_size(256, 256), amdgpu_waves_per_eu(2, 2)))
void lstm_fused(
    const float* __restrict__ x,      // [B, T, 1]
    const float* __restrict__ W_ih,   // [4H, 1]
    const float* __restrict__ W_hh,   // [4H, H]
    const float* __restrict__ b_ih,   // [4H]
    const float* __restrict__ b_hh,   // [4H]
    const float* __restrict__ W_out,  // [1, H]
    const float* __restrict__ b_out,  // [1]
    float* __restrict__ out)          // [B, T, 1]
{
    const int tid = threadIdx.x;
    const int l   = tid & 1;                        // parity within pair
    const int vc  = blockIdx.x * 128 + (tid >> 1);  // virtual chain 0..65535
    const int seg = vc >> 12;                       // block-uniform (32 blk/seg)
    const int b   = vc & (BATCH - 1);

    const int t_main = seg * SEGLEN;
    const int t0     = seg ? (t_main - WARM) : 0;
    const int tend   = t_main + SEGLEN;

    // w16[unit][gate][slot]: 6 f16 pairs per row = [own h pairs | other h
    // pairs], slot2 of each parity group carries (whh_{5p+4}, p==0?wih:bias).
    h2 w16[5][4][6];
    #pragma unroll
    for (int k = 0; k < 5; ++k) {
        const int u = 5 * l + k;
        #pragma unroll
        for (int g = 0; g < 4; ++g) {
            const int   r  = g * HID + u;           // PyTorch gate order i,f,g,o
            const float sc = (g == 2) ? (-2.0f * LOG2E) : (-LOG2E);
            #pragma unroll
            for (int half = 0; half < 2; ++half) {
                const int p = half ? (1 - l) : l;   // parity of this slot group
                const float a0 = W_hh[r * HID + 5 * p + 0] * sc;
                const float a1 = W_hh[r * HID + 5 * p + 1] * sc;
                const float a2 = W_hh[r * HID + 5 * p + 2] * sc;
                const float a3 = W_hh[r * HID + 5 * p + 3] * sc;
                const float a4 = W_hh[r * HID + 5 * p + 4] * sc;
                const float ay = (p == 0) ? (W_ih[r] * sc)
                                          : ((b_ih[r] + b_hh[r]) * sc);
                w16[k][g][3 * half + 0] = h2{(_Float16)a0, (_Float16)a1};
                w16[k][g][3 * half + 1] = h2{(_Float16)a2, (_Float16)a3};
                w16[k][g][3 * half + 2] = h2{(_Float16)a4, (_Float16)ay};
            }
        }
    }
    const h2 wo0 = h2{(_Float16)W_out[5 * l + 0], (_Float16)W_out[5 * l + 1]};
    const h2 wo1 = h2{(_Float16)W_out[5 * l + 2], (_Float16)W_out[5 * l + 3]};
    const h2 wo2 = h2{(_Float16)W_out[5 * l + 4], (_Float16)0.0f};
    const float bout = b_out[0];

    const float* xptr = x   + (size_t)b * SEQT + 4 * l;
    float*       optr = out + (size_t)b * SEQT + 4 * l;

    float ho[5] = {0.f, 0.f, 0.f, 0.f, 0.f};
    float cc[5] = {0.f, 0.f, 0.f, 0.f, 0.f};
    float keep[4] = {0.f, 0.f, 0.f, 0.f};
    float xq[4], xqn[4];

    {   // first chunk's x: lane l holds x[t0+4l .. t0+4l+3]
        const float4 a = *(const float4*)(xptr + t0);
        xq[0] = a.x; xq[1] = a.y; xq[2] = a.z; xq[3] = a.w;
    }

    for (int tc = t0; tc < tend; tc += 8) {
        if (tc + 8 < tend) {
            const float4 a = *(const float4*)(xptr + tc + 8);
            xqn[0] = a.x; xqn[1] = a.y; xqn[2] = a.z; xqn[3] = a.w;
        }
        const bool store_ok = (tc > t_main);
        STEP(0, store_ok)
        STEP(1, false) STEP(2, false) STEP(3, false)
        STEP(4, false) STEP(5, false) STEP(6, false) STEP(7, false)
        #pragma unroll
        for (int i = 0; i < 4; ++i) xq[i] = xqn[i];
    }

    // epilogue: out[tend-1] from final h, store last chunk
    {
        const int o0 = pk16(ho[0], ho[1]);
        const int o1 = pk16(ho[2], ho[3]);
        const int o2 = pk16(ho[4], 0.0f);          // t slot weight is 0
        float rp = fdot2(__builtin_bit_cast(h2, o2), wo2,
                   fdot2(__builtin_bit_cast(h2, o1), wo1,
                   fdot2(__builtin_bit_cast(h2, o0), wo0, 0.0f)));
        rp += pswapf(rp);
        const float r = rp + bout;
        if (l == 1) keep[3] = r;                   // position 7
        *(float4*)(optr + tend - 8) = make_float4(keep[0], keep[1],
                                                  keep[2], keep[3]);
    }
}

extern "C" void kernel_launch(void* const* d_in, const int* in_sizes, int n_in,
                              void* d_out, int out_size, void* d_ws, size_t ws_size,
                              hipStream_t stream) {
    const float* x     = (const float*)d_in[0];
    const float* W_ih  = (const float*)d_in[1];
    const float* W_hh  = (const float*)d_in[2];
    const float* b_ih  = (const float*)d_in[3];
    const float* b_hh  = (const float*)d_in[4];
    const float* W_out = (const float*)d_in[5];
    const float* b_out = (const float*)d_in[6];
    float* out = (float*)d_out;

    dim3 grid(NSEG * BATCH / 128);   // 512 blocks x 128 vchains -> 2048 waves
    dim3 block(256);
    lstm_fused<<<grid, block, 0, stream>>>(x, W_ih, W_hh, b_ih, b_hh,
                                           W_out, b_out, out);
}

// Round 11
// 193.743 us; speedup vs baseline: 1.5816x; 1.4769x over previous
//
#include <hip/hip_runtime.h>

#define BATCH  4096
#define SEQT   2048
#define HID    10
#define NSEG   16
#define SEGLEN (SEQT / NSEG)     // 128
#define WARM   64

#define LOG2E 1.44269504088896340736f

typedef _Float16 halfx8   __attribute__((ext_vector_type(8)));
typedef float    floatx16 __attribute__((ext_vector_type(16)));

__device__ __forceinline__ float rcp_f(float v) { return __builtin_amdgcn_rcpf(v); }
__device__ __forceinline__ float exp2_f(float v) {
#if __has_builtin(__builtin_amdgcn_exp2f)
    return __builtin_amdgcn_exp2f(v);
#else
    return __expf(v * 0.6931471805599453f);
#endif
}
__device__ __forceinline__ int pk16(float a, float b) {
    return __builtin_bit_cast(int, __builtin_amdgcn_cvt_pkrtz(a, b));
}

union B4 { int i[4]; halfx8 v; };
union A8 { _Float16 h[8]; halfx8 v; };

// One step, S = literal 0..7.
// MFMA#1: A1 = W rows 4u+g for units 0..7 (row m, k per K-map below).
// MFMA#2: A2 rows: m<4 -> unit8 gate m; m in 4..7 -> unit9 gate m-4;
//         m==8 -> W_out row (unscaled); else 0.
// C/D map (verified, m74/m101): row = (reg&3) + 8*(reg>>2) + 4*(lane>>5).
//   => A2 row 8 lands on reg 4 for p==0 lanes: out-dot = d2[4].  (R10 bug:
//   used d2[8] = row 16 = zero row -> constant output.)
// K-map: k=0..4 -> h{0,2,4,6,8}; k=5 -> x; k=8..12 -> h{1,3,5,7,9}; rest 0.
// B frag (lane holds k=8p+j, col=lane&31) == lane's OWN (ho[0..4], x) ->
// exchange is just 3 cvt_pkrtz, no cross-lane ops at all.
// Biases (pre-scaled) ride the constant C operand.
// Gate algebra (rows pre-scaled -log2e, tanh row -2log2e):
//   i=1/(1+Ei), f=1/(1+Ef), g=(1-Eg)/(1+Eg), o=1/(1+Eo);
//   c' = (c*Pi*Pg + Mg*Pf)/(Pf*Pi*Pg);  h = (1-Ec)/(Po*(1+Ec)).
#define STEP(S, STORE_OK)                                                      \
  {                                                                            \
    B4 bu;                                                                     \
    bu.i[0] = pk16(ho[0], ho[1]);                                              \
    bu.i[1] = pk16(ho[2], ho[3]);                                              \
    bu.i[2] = pk16(ho[4], xq[(S)]);                                            \
    bu.i[3] = 0;                                                               \
    const floatx16 d1 =                                                        \
        __builtin_amdgcn_mfma_f32_32x32x16_f16(a1.v, bu.v, cb1, 0, 0, 0);      \
    const floatx16 d2 =                                                        \
        __builtin_amdgcn_mfma_f32_32x32x16_f16(a2.v, bu.v, cb2, 0, 0, 0);      \
    keep[((S) + 7) & 7] = d2[4] + bout;     /* out[t-1], valid on p==0 */      \
    if ((S) == 0 && (STORE_OK) && lp0) {                                       \
      *(float4*)(optr + tc - 8) = make_float4(keep[0], keep[1],                \
                                              keep[2], keep[3]);               \
      *(float4*)(optr + tc - 4) = make_float4(keep[4], keep[5],                \
                                              keep[6], keep[7]);               \
    }                                                                          \
    _Pragma("unroll")                                                          \
    for (int j = 0; j < 5; ++j) {                                              \
      const float pi = (j < 4) ? d1[4 * j + 0] : d2[0];                        \
      const float pf = (j < 4) ? d1[4 * j + 1] : d2[1];                        \
      const float pg = (j < 4) ? d1[4 * j + 2] : d2[2];                        \
      const float po = (j < 4) ? d1[4 * j + 3] : d2[3];                        \
      const float Ei = exp2_f(pi), Ef = exp2_f(pf);                            \
      const float Eg = exp2_f(pg), Eo = exp2_f(po);                            \
      const float Pi = 1.0f + Ei, Pf = 1.0f + Ef;                              \
      const float Pg = 1.0f + Eg, Po = 1.0f + Eo;                              \
      const float Mg = 1.0f - Eg;                                              \
      const float A   = Pi * Pg;                                               \
      const float den = Pf * A;                                                \
      const float num = fmaf(cc[j], A, Mg * Pf);                               \
      const float cn  = num * rcp_f(den);                                      \
      cc[j] = cn;                                                              \
      const float Ec = exp2_f(cn * (-2.0f * LOG2E));                           \
      ho[j] = (1.0f - Ec) * rcp_f(Po * (1.0f + Ec));                           \
    }                                                                          \
    __builtin_amdgcn_sched_barrier(0);                                         \
  }

// Lane pair (m, m+32) serves chain col m; half p = lane>>5 owns units
// {2j+p : j<4} U {8+p} (the MFMA C/D row->lane mapping for rows 4u+g).
// 32 chains/wave. 16-way sequence split w/ 64-step warm-up -> 65536
// vchains -> 2048 waves = 2/SIMD.
__global__
__attribute__((amdgpu_flat_work_group_size(256, 256), amdgpu_waves_per_eu(2, 2)))
void lstm_fused(
    const float* __restrict__ x,      // [B, T, 1]
    const float* __restrict__ W_ih,   // [4H, 1]
    const float* __restrict__ W_hh,   // [4H, H]
    const float* __restrict__ b_ih,   // [4H]
    const float* __restrict__ b_hh,   // [4H]
    const float* __restrict__ W_out,  // [1, H]
    const float* __restrict__ b_out,  // [1]
    float* __restrict__ out)          // [B, T, 1]
{
    const int tid  = threadIdx.x;
    const int lane = tid & 63;
    const int p    = lane >> 5;                    // k-half / unit parity
    const int m    = lane & 31;                    // A row / chain col
    const bool lp0 = (lane < 32);
    const int wv   = tid >> 6;                     // wave within block
    const int vc   = blockIdx.x * 128 + wv * 32 + m;
    const int seg  = vc >> 12;                     // block-uniform
    const int b    = vc & (BATCH - 1);

    const int t_main = seg * SEGLEN;
    const int t0     = seg ? (t_main - WARM) : 0;
    const int tend   = t_main + SEGLEN;

    // weight at K-slot k for pytorch row r, scale sc
    auto wslot = [&](int r, float sc, int k) -> float {
        if (k < 5)  return W_hh[r * HID + 2 * k] * sc;          // units 0,2,4,6,8
        if (k == 5) return W_ih[r] * sc;                        // x
        if (k < 8)  return 0.0f;
        if (k < 13) return W_hh[r * HID + 2 * (k - 8) + 1] * sc; // units 1,3,5,7,9
        return 0.0f;
    };

    A8 a1, a2;
    {   // A1: row m = 4u+g -> units 0..7
        const int u = m >> 2, g = m & 3;
        const int r = g * HID + u;                 // pytorch gate order i,f,g,o
        const float sc = (g == 2) ? (-2.0f * LOG2E) : (-LOG2E);
        #pragma unroll
        for (int j = 0; j < 8; ++j)
            a1.h[j] = (_Float16)wslot(r, sc, 8 * p + j);
    }
    {   // A2: rows 0..3 unit8, 4..7 unit9, 8 = W_out, rest 0
        #pragma unroll
        for (int j = 0; j < 8; ++j) {
            const int k = 8 * p + j;
            float v = 0.0f;
            if (m < 8) {
                const int u = 8 + (m >> 2), g = m & 3;
                const float sc = (g == 2) ? (-2.0f * LOG2E) : (-LOG2E);
                v = wslot(g * HID + u, sc, k);
            } else if (m == 8) {
                if (k < 5)                 v = W_out[2 * k];
                else if (k >= 8 && k < 13) v = W_out[2 * (k - 8) + 1];
            }
            a2.h[j] = (_Float16)v;
        }
    }

    floatx16 cb1, cb2;                             // bias C-operands (constant)
    #pragma unroll
    for (int reg = 0; reg < 16; ++reg) {
        const int g = reg & 3, t = reg >> 2;
        const int u = 2 * t + p;
        const float sc = (g == 2) ? (-2.0f * LOG2E) : (-LOG2E);
        cb1[reg] = (b_ih[g * HID + u] + b_hh[g * HID + u]) * sc;
        float v2 = 0.0f;
        if (reg < 4) {
            const int uu = 8 + p, gg = reg;
            const float sc2 = (gg == 2) ? (-2.0f * LOG2E) : (-LOG2E);
            v2 = (b_ih[gg * HID + uu] + b_hh[gg * HID + uu]) * sc2;
        }
        cb2[reg] = v2;
    }
    const float bout = b_out[0];

    const float* xptr = x   + (size_t)b * SEQT;
    float*       optr = out + (size_t)b * SEQT;

    float ho[5] = {0.f, 0.f, 0.f, 0.f, 0.f};       // own units' h
    float cc[5] = {0.f, 0.f, 0.f, 0.f, 0.f};
    float keep[8] = {0.f, 0.f, 0.f, 0.f, 0.f, 0.f, 0.f, 0.f};
    float xq[8], xqn[8];

    {   // first chunk's x (both lanes of a pair load the same row)
        const float4 a = *(const float4*)(xptr + t0);
        const float4 c = *(const float4*)(xptr + t0 + 4);
        xq[0] = a.x; xq[1] = a.y; xq[2] = a.z; xq[3] = a.w;
        xq[4] = c.x; xq[5] = c.y; xq[6] = c.z; xq[7] = c.w;
    }

    for (int tc = t0; tc < tend; tc += 8) {
        if (tc + 8 < tend) {
            const float4 a = *(const float4*)(xptr + tc + 8);
            const float4 c = *(const float4*)(xptr + tc + 12);
            xqn[0] = a.x; xqn[1] = a.y; xqn[2] = a.z; xqn[3] = a.w;
            xqn[4] = c.x; xqn[5] = c.y; xqn[6] = c.z; xqn[7] = c.w;
        }
        const bool store_ok = (tc > t_main);
        STEP(0, store_ok)
        STEP(1, false) STEP(2, false) STEP(3, false)
        STEP(4, false) STEP(5, false) STEP(6, false) STEP(7, false)
        #pragma unroll
        for (int i = 0; i < 8; ++i) xq[i] = xqn[i];
    }

    // epilogue: out[tend-1] = W_out . h_{tend-1} via one extra MFMA#2
    {
        B4 bu;
        bu.i[0] = pk16(ho[0], ho[1]);
        bu.i[1] = pk16(ho[2], ho[3]);
        bu.i[2] = pk16(ho[4], 0.0f);
        bu.i[3] = 0;
        const floatx16 d2 =
            __builtin_amdgcn_mfma_f32_32x32x16_f16(a2.v, bu.v, cb2, 0, 0, 0);
        keep[7] = d2[4] + bout;                    // row 8 = W_out row (p==0)
        if (lp0) {
            *(float4*)(optr + tend - 8) = make_float4(keep[0], keep[1],
                                                      keep[2], keep[3]);
            *(float4*)(optr + tend - 4) = make_float4(keep[4], keep[5],
                                                      keep[6], keep[7]);
        }
    }
}

extern "C" void kernel_launch(void* const* d_in, const int* in_sizes, int n_in,
                              void* d_out, int out_size, void* d_ws, size_t ws_size,
                              hipStream_t stream) {
    const float* x     = (const float*)d_in[0];
    const float* W_ih  = (const float*)d_in[1];
    const float* W_hh  = (const float*)d_in[2];
    const float* b_ih  = (const float*)d_in[3];
    const float* b_hh  = (const float*)d_in[4];
    const float* W_out = (const float*)d_in[5];
    const float* b_out = (const float*)d_in[6];
    float* out = (float*)d_out;

    dim3 grid(NSEG * BATCH / 128);   // 512 blocks x 4 waves x 32 chains
    dim3 block(256);
    lstm_fused<<<grid, block, 0, stream>>>(x, W_ih, W_hh, b_ih, b_hh,
                                           W_out, b_out, out);
}